// Round 5
// baseline (847.149 us; speedup 1.0000x reference)
//
#include <hip/hip_runtime.h>
#include <math.h>

#define H_DIM 1024

typedef _Float16 half8 __attribute__((ext_vector_type(8)));
typedef float f32x16 __attribute__((ext_vector_type(16)));

__device__ __forceinline__ void gload_lds16(const void* g, void* l) {
    __builtin_amdgcn_global_load_lds((const __attribute__((address_space(1))) uint32_t*)g,
                                     (__attribute__((address_space(3))) uint32_t*)l,
                                     16, 0, 0);
}

// ---- pack W1 [512][1024] fp32 -> two fp16 planes, 32x32x16-B-fragment order ----
// Bpack half-offset: ((ks*4 + ksub*2 + plane)*16 + nf)*512 + lane*8 + j
// lane holds B[k][n] = W1[n][k], n = nf*32+(lane&31), k = ks*32+ksub*16+(lane>>5)*8+j
__global__ void pack_w1_kernel(const float* __restrict__ W1, _Float16* __restrict__ Bpack) {
    int tid  = blockIdx.x * 256 + threadIdx.x;   // 0..65535
    int lane = tid & 63;
    int nf   = (tid >> 6) & 15;
    int ksub = (tid >> 10) & 1;
    int ks   = tid >> 11;                        // 0..31
    int n  = nf * 32 + (lane & 31);
    int k0 = ks * 32 + ksub * 16 + (lane >> 5) * 8;
    const float* src = W1 + (size_t)n * H_DIM + k0;
    float4 v0 = *(const float4*)src;
    float4 v1 = *(const float4*)(src + 4);
    float xs[8] = {v0.x, v0.y, v0.z, v0.w, v1.x, v1.y, v1.z, v1.w};
    half8 h0, h1;
#pragma unroll
    for (int j = 0; j < 8; ++j) {
        _Float16 a = (_Float16)xs[j];
        float r = xs[j] - (float)a;
        h0[j] = a;
        h1[j] = (_Float16)(r * 2048.0f);
    }
    size_t o0 = ((size_t)(ks * 4 + ksub * 2 + 0) * 16 + nf) * 512 + lane * 8;
    size_t o1 = ((size_t)(ks * 4 + ksub * 2 + 1) * 16 + nf) * 512 + lane * 8;
    *(half8*)(Bpack + o0) = h0;
    *(half8*)(Bpack + o1) = h1;
}

// ---- fused scorer, fp16-split via 32x32x16 MFMA, A in registers ----
// block 128 rows x 128 cols (nb quarter of N=512); 2x2 waves of 64x64.
// LDS: B dbuf 2 x 16 KB; red float[128][65] overlays for epilogue.
__global__ __launch_bounds__(256, 2)
void score_mfma_kernel(const float* __restrict__ X,
                       const _Float16* __restrict__ Bpack,
                       const float* __restrict__ b1,
                       const float* __restrict__ W2,
                       float* __restrict__ sparts, int tot_tokens) {
    __shared__ __align__(16) char smem[33280];   // max(2*16384, 128*65*4)

    const int t    = threadIdx.x;
    const int w    = t >> 6;
    const int lane = t & 63;
    const int wr   = w >> 1;                     // M half within block
    const int wc   = w & 1;                      // N half within block

    // XCD-chunked swizzle: the 4 nb-blocks of one m-row stay on one XCD.
    const int nblk    = gridDim.x;
    const int chunk   = nblk >> 3;
    const int logical = ((int)blockIdx.x & 7) * chunk + ((int)blockIdx.x >> 3);
    const int nb      = logical & 3;
    const int mblk    = logical >> 2;
    const size_t m0   = (size_t)mblk * 128 + wr * 64;

    // A fragment addressing: lane covers row (lane&31), k-window (lane>>5)*8
    const int arow = lane & 31;
    const int khi  = (lane >> 5) * 8;
    const float* aptr0 = X + (m0 + arow) * H_DIM + khi;        // mf=0 rows
    const float* aptr1 = X + (m0 + 32 + arow) * H_DIM + khi;   // mf=1 rows

    f32x16 acc1[2][2] = {};
    f32x16 acc2[2][2] = {};

    float4 av[8];           // [mf*4 + ksub*2 + half]
    half8  ah0[4], ah1[4];  // [mf*2 + ksub]

#define LOAD_A(ks)                                                   \
    do {                                                             \
        const float* p0 = aptr0 + (ks) * 32;                         \
        const float* p1 = aptr1 + (ks) * 32;                         \
        av[0] = *(const float4*)(p0);                                \
        av[1] = *(const float4*)(p0 + 4);                            \
        av[2] = *(const float4*)(p0 + 16);                           \
        av[3] = *(const float4*)(p0 + 20);                           \
        av[4] = *(const float4*)(p1);                                \
        av[5] = *(const float4*)(p1 + 4);                            \
        av[6] = *(const float4*)(p1 + 16);                           \
        av[7] = *(const float4*)(p1 + 20);                           \
    } while (0)

#define CONVERT_A()                                                  \
    do {                                                             \
        _Pragma("unroll") for (int q = 0; q < 4; ++q) {              \
            float xs[8] = {av[q * 2].x, av[q * 2].y, av[q * 2].z, av[q * 2].w, \
                           av[q * 2 + 1].x, av[q * 2 + 1].y, av[q * 2 + 1].z, av[q * 2 + 1].w}; \
            half8 h0, h1;                                            \
            _Pragma("unroll") for (int j = 0; j < 8; ++j) {          \
                _Float16 a = (_Float16)xs[j];                        \
                float r = xs[j] - (float)a;                          \
                h0[j] = a;                                           \
                h1[j] = (_Float16)(r * 2048.0f);                     \
            }                                                        \
            ah0[q] = h0;                                             \
            ah1[q] = h1;                                             \
        }                                                            \
    } while (0)

    // stage 16 KB of B for K-step ks: 4 slabs (ksub,plane) x 4 KB, linear
#define STAGE_B(ks, buf)                                             \
    do {                                                             \
        const _Float16* src = Bpack + (size_t)(ks) * 32768 + nb * 2048 + t * 8; \
        char* dst = smem + (buf) * 16384 + t * 16;                   \
        _Pragma("unroll") for (int p = 0; p < 4; ++p)                \
            gload_lds16(src + p * 8192, dst + p * 4096);             \
    } while (0)

    // ---- prologue ----
    LOAD_A(0);
    STAGE_B(0, 0);
    asm volatile("s_waitcnt vmcnt(0)" ::: "memory");
    __builtin_amdgcn_sched_barrier(0);
    __builtin_amdgcn_s_barrier();

    int cur = 0;
    for (int ks = 0; ks < 32; ++ks) {
        const int nxt = cur ^ 1;
        if (ks < 31) STAGE_B(ks + 1, nxt);   // 4 gload_lds, oldest vmem
        CONVERT_A();                          // consumes av (compiler waits on A loads)
        if (ks < 31) LOAD_A(ks + 1);          // 8 loads, stay in flight over barrier

        const char* bb = smem + cur * 16384;
#pragma unroll
        for (int ksub = 0; ksub < 2; ++ksub) {
            half8 b00 = *(const half8*)(bb + ((ksub * 2 + 0) * 4 + wc * 2 + 0) * 1024 + lane * 16);
            half8 b01 = *(const half8*)(bb + ((ksub * 2 + 0) * 4 + wc * 2 + 1) * 1024 + lane * 16);
            half8 b10 = *(const half8*)(bb + ((ksub * 2 + 1) * 4 + wc * 2 + 0) * 1024 + lane * 16);
            half8 b11 = *(const half8*)(bb + ((ksub * 2 + 1) * 4 + wc * 2 + 1) * 1024 + lane * 16);
            __builtin_amdgcn_s_setprio(1);
            acc1[0][0] = __builtin_amdgcn_mfma_f32_32x32x16_f16(ah0[0 + ksub], b00, acc1[0][0], 0, 0, 0);
            acc1[0][1] = __builtin_amdgcn_mfma_f32_32x32x16_f16(ah0[0 + ksub], b01, acc1[0][1], 0, 0, 0);
            acc1[1][0] = __builtin_amdgcn_mfma_f32_32x32x16_f16(ah0[2 + ksub], b00, acc1[1][0], 0, 0, 0);
            acc1[1][1] = __builtin_amdgcn_mfma_f32_32x32x16_f16(ah0[2 + ksub], b01, acc1[1][1], 0, 0, 0);
            acc2[0][0] = __builtin_amdgcn_mfma_f32_32x32x16_f16(ah0[0 + ksub], b10, acc2[0][0], 0, 0, 0);
            acc2[0][1] = __builtin_amdgcn_mfma_f32_32x32x16_f16(ah0[0 + ksub], b11, acc2[0][1], 0, 0, 0);
            acc2[1][0] = __builtin_amdgcn_mfma_f32_32x32x16_f16(ah0[2 + ksub], b10, acc2[1][0], 0, 0, 0);
            acc2[1][1] = __builtin_amdgcn_mfma_f32_32x32x16_f16(ah0[2 + ksub], b11, acc2[1][1], 0, 0, 0);
            acc2[0][0] = __builtin_amdgcn_mfma_f32_32x32x16_f16(ah1[0 + ksub], b00, acc2[0][0], 0, 0, 0);
            acc2[0][1] = __builtin_amdgcn_mfma_f32_32x32x16_f16(ah1[0 + ksub], b01, acc2[0][1], 0, 0, 0);
            acc2[1][0] = __builtin_amdgcn_mfma_f32_32x32x16_f16(ah1[2 + ksub], b00, acc2[1][0], 0, 0, 0);
            acc2[1][1] = __builtin_amdgcn_mfma_f32_32x32x16_f16(ah1[2 + ksub], b01, acc2[1][1], 0, 0, 0);
            __builtin_amdgcn_s_setprio(0);
        }

        if (ks < 31) {
            // drain only this iteration's 4 gload_lds; the 8 A-loads keep flying
            asm volatile("s_waitcnt vmcnt(8)" ::: "memory");
            __builtin_amdgcn_sched_barrier(0);
            __builtin_amdgcn_s_barrier();
        }
        cur = nxt;
    }

    // ---- epilogue: h = acc1 + acc2/2048 + b1; exact gelu; *W2; reduce ----
    __syncthreads();   // all LDS frag reads done before red overlays B bufs
    float* red = (float*)smem;  // [128][65]
    float b1v[2], w2v[2];
#pragma unroll
    for (int nfl = 0; nfl < 2; ++nfl) {
        int c = nb * 128 + wc * 64 + nfl * 32 + (lane & 31);
        b1v[nfl] = b1[c];
        w2v[nfl] = W2[c];
    }
#pragma unroll
    for (int mf = 0; mf < 2; ++mf) {
#pragma unroll
        for (int i = 0; i < 16; ++i) {
            float s = 0.f;
#pragma unroll
            for (int nfl = 0; nfl < 2; ++nfl) {
                float h = acc1[mf][nfl][i] + acc2[mf][nfl][i] * (1.0f / 2048.0f) + b1v[nfl];
                float g = 0.5f * h * (1.0f + erff(h * 0.70710678118654752f));
                s = fmaf(g, w2v[nfl], s);
            }
            int row = wr * 64 + mf * 32 + (i & 3) + 8 * (i >> 2) + 4 * (lane >> 5);
            red[row * 65 + wc * 32 + (lane & 31)] = s;
        }
    }
    __syncthreads();
    if (t < 128) {
        float s = 0.f;
#pragma unroll
        for (int c = 0; c < 64; ++c) s += red[t * 65 + c];
        sparts[(size_t)nb * tot_tokens + (size_t)mblk * 128 + t] = s;
    }
}

// ---- per-segment top-quota selection + gather (scores = sum of 4 partials) ----
__global__ void select_gather_kernel(const float* __restrict__ X,
                                     const float* __restrict__ sparts,
                                     float* __restrict__ out,
                                     int N, int seg_len, int quota, int n_seg,
                                     int tot_tokens) {
    const int seg = blockIdx.x;
    const int b   = blockIdx.y;
    __shared__ float sc[64];
    __shared__ int sel_idx[64];
    const int t = threadIdx.x;
    if (t < seg_len) {
        size_t tok = (size_t)b * N + (size_t)seg * seg_len + t;
        sc[t] = sparts[tok] + sparts[tok + tot_tokens]
              + sparts[tok + 2 * (size_t)tot_tokens] + sparts[tok + 3 * (size_t)tot_tokens];
    }
    __syncthreads();
    if (t == 0) {
        unsigned long long mask = 0ull;
        for (int it = 0; it < quota; ++it) {
            float best = 0.f;
            int bi = 0;
            bool found = false;
            for (int i = 0; i < seg_len; ++i) {
                if (!((mask >> i) & 1ull)) {
                    if (!found || sc[i] > best) { best = sc[i]; bi = i; found = true; }
                }
            }
            mask |= (1ull << bi);
        }
        int c = 0;
        for (int i = 0; i < seg_len; ++i)
            if ((mask >> i) & 1ull) sel_idx[c++] = i;  // ascending == sorted output
    }
    __syncthreads();
    const size_t HV = H_DIM / 4;
    const float4* xb = (const float4*)X + ((size_t)b * N + (size_t)seg * seg_len) * HV;
    float4* ob = (float4*)out + ((size_t)b * n_seg * quota + (size_t)seg * quota) * HV;
    for (int j = 0; j < quota; ++j) {
        const float4* srow = xb + (size_t)sel_idx[j] * HV;
        float4* drow = ob + (size_t)j * HV;
        for (int c = t; c < (int)HV; c += blockDim.x) drow[c] = srow[c];
    }
}

extern "C" void kernel_launch(void* const* d_in, const int* in_sizes, int n_in,
                              void* d_out, int out_size, void* d_ws, size_t ws_size,
                              hipStream_t stream) {
    const float* X  = (const float*)d_in[0];
    const float* W1 = (const float*)d_in[1];
    const float* b1 = (const float*)d_in[2];
    const float* W2 = (const float*)d_in[3];
    float* out = (float*)d_out;

    const int Hh = in_sizes[2];                        // 512
    const int H  = Hh * 2;                             // 1024
    const long long TOT = (long long)in_sizes[0] / H;  // 147456 tokens
    const int B = 256;
    const int N = (int)(TOT / B);                      // 576
    const int n_seg = 32;
    const int seg_len = N / n_seg;                     // 18
    const int rows_per_b = out_size / (B * H);         // 288
    const int quota = rows_per_b / n_seg;              // 9

    _Float16* Bpack = (_Float16*)d_ws;                                  // 2 MB
    float* sparts   = (float*)((char*)d_ws + (size_t)2 * 1024 * 1024);  // 4*TOT floats

    hipLaunchKernelGGL(pack_w1_kernel, dim3(256), dim3(256), 0, stream, W1, Bpack);

    const int nblk = (int)(TOT / 128) * 4;             // 4608, divisible by 8
    hipLaunchKernelGGL(score_mfma_kernel, dim3(nblk), dim3(256), 0, stream,
                       X, Bpack, b1, W2, sparts, (int)TOT);

    dim3 sg(n_seg, B);
    hipLaunchKernelGGL(select_gather_kernel, sg, dim3(256), 0, stream,
                       X, sparts, out, N, seg_len, quota, n_seg, (int)TOT);
}

// Round 6
// 737.707 us; speedup vs baseline: 1.1484x; 1.1484x over previous
//
#include <hip/hip_runtime.h>
#include <math.h>

#define H_DIM 1024

typedef _Float16 half8 __attribute__((ext_vector_type(8)));
typedef float f32x16 __attribute__((ext_vector_type(16)));

__device__ __forceinline__ void gload_lds16(const void* g, void* l) {
    __builtin_amdgcn_global_load_lds((const __attribute__((address_space(1))) uint32_t*)g,
                                     (__attribute__((address_space(3))) uint32_t*)l,
                                     16, 0, 0);
}

// ---- pack W1 [512][1024] fp32 -> two fp16 planes, 32x32x16-B-fragment order ----
// Bpack halves offset: kt*32768 + nb*16384 + p*8192 + ksub*4096 + nf*512 + slot*8 + j
// slot = ((k>>3)&1)*32 + (n&31); lane holds B[k][n]=W1[n][k], k=(lane>>5)*8+j within ksub.
__global__ void pack_w1_kernel(const float* __restrict__ W1, _Float16* __restrict__ Bpack) {
    int tid = blockIdx.x * 256 + threadIdx.x;   // 0..65535 = 512 n x 128 k-octets
    int q   = tid & 127;                        // k-octet
    int n   = tid >> 7;
    int kt = q >> 2, ksub = (q >> 1) & 1, hi = q & 1;
    int nb = n >> 8, nf = (n >> 5) & 7, nlo = n & 31;
    const float* src = W1 + (size_t)n * H_DIM + q * 8;
    float4 v0 = *(const float4*)src;
    float4 v1 = *(const float4*)(src + 4);
    float xs[8] = {v0.x, v0.y, v0.z, v0.w, v1.x, v1.y, v1.z, v1.w};
    half8 h0, h1;
#pragma unroll
    for (int j = 0; j < 8; ++j) {
        _Float16 a = (_Float16)xs[j];
        float r = xs[j] - (float)a;
        h0[j] = a;
        h1[j] = (_Float16)(r * 2048.0f);
    }
    size_t base = (size_t)kt * 32768 + (size_t)nb * 16384 + (size_t)ksub * 4096
                + (size_t)nf * 512 + (size_t)(hi * 32 + nlo) * 8;
    *(half8*)(Bpack + base)        = h0;   // plane 0
    *(half8*)(Bpack + base + 8192) = h1;   // plane 1
}

// ---- fused scorer: 3-phase-per-K-tile (8-phase-style) fp16-split MFMA GEMM ----
// BM=128, BN=256 (nb half of 512), BK=32. 8 waves (2M x 4N), wave tile 64x64.
// LDS: 2 bufs x (A 16 KB + B 32 KB) = 96 KB; red[128][132] overlays for epilogue.
//   A frag f=(pl*4+rg)*2+ksub at f*1024 + lane*16 (rg = row/32 within block)
//   B frag at ((pl*2+ksub)*8 + nf8)*1024 + lane*16 (nf8 = col/32 within 256)
__global__ __launch_bounds__(512, 2)
void score_mfma_kernel(const float* __restrict__ X,
                       const _Float16* __restrict__ Bpack,
                       const float* __restrict__ b1,
                       const float* __restrict__ W2,
                       float* __restrict__ sparts, int tot_tokens) {
    __shared__ __align__(16) char smem[98304];

    const int t    = threadIdx.x;   // 0..511
    const int w    = t >> 6;
    const int lane = t & 63;
    const int wr   = w >> 2;        // 0..1 (M)
    const int wc   = w & 3;         // 0..3 (N)

    // bijective XCD-chunked swizzle (nwg = 2304 divisible by 8); the two nb
    // blocks of one mblk are logically adjacent -> same XCD -> L2-shared X.
    const int nwg     = (int)gridDim.x;
    const int chunk   = nwg >> 3;
    const int logical = ((int)blockIdx.x & 7) * chunk + ((int)blockIdx.x >> 3);
    const int nb      = logical & 1;
    const int mblk    = logical >> 1;
    const size_t m0   = (size_t)mblk * 128;

    // A staging role: thread t -> row t>>2 (0..127), k-octet t&3
    const int r_   = t >> 2;
    const int kq   = t & 3;
    const int rg_  = r_ >> 5;
    const int aks  = kq >> 1;
    const int awsl = (kq & 1) * 32 + (r_ & 31);
    const float* aRow = X + (m0 + r_) * H_DIM + kq * 8;

    f32x16 acc1[2][2] = {};
    f32x16 acc2[2][2] = {};
    float4 av0, av1;

#define A_LOAD(kt)                                                        \
    do {                                                                  \
        av0 = *(const float4*)(aRow + (kt) * 32);                         \
        av1 = *(const float4*)(aRow + (kt) * 32 + 4);                     \
    } while (0)

#define A_CONVERT_WRITE(abase)                                            \
    do {                                                                  \
        float xs[8] = {av0.x, av0.y, av0.z, av0.w, av1.x, av1.y, av1.z, av1.w}; \
        half8 h0, h1;                                                     \
        _Pragma("unroll") for (int j = 0; j < 8; ++j) {                   \
            _Float16 a = (_Float16)xs[j];                                 \
            float r = xs[j] - (float)a;                                   \
            h0[j] = a;                                                    \
            h1[j] = (_Float16)(r * 2048.0f);                              \
        }                                                                 \
        *(half8*)((abase) + ((rg_ * 2 + aks)) * 1024 + awsl * 16) = h0;   \
        *(half8*)((abase) + ((4 + rg_) * 2 + aks) * 1024 + awsl * 16) = h1; \
    } while (0)

#define B_STAGE(kt, bbase)                                                \
    do {                                                                  \
        const _Float16* src = Bpack + (size_t)(kt) * 32768 + (size_t)nb * 16384 + t * 8; \
        _Pragma("unroll") for (int p = 0; p < 4; ++p)                     \
            gload_lds16(src + p * 4096, (bbase) + t * 16 + p * 8192);     \
    } while (0)

    // ---- prologue: stage tile 0 ----
    A_LOAD(0);
    B_STAGE(0, smem + 16384);
    A_CONVERT_WRITE(smem);
    asm volatile("s_waitcnt vmcnt(0) lgkmcnt(0)" ::: "memory");
    __builtin_amdgcn_sched_barrier(0);
    __builtin_amdgcn_s_barrier();

    int cur = 0;
    for (int kt = 0; kt < 32; ++kt) {
        char* Ac = smem + cur * 49152;
        char* Bc = Ac + 16384;
        char* An = smem + (cur ^ 1) * 49152;
        char* Bn = An + 16384;
        half8 a0[4], a1[4], b0[4], b1f[4];

        // ================= phase 1: acc1 += a0*b0 =================
#pragma unroll
        for (int mf = 0; mf < 2; ++mf)
#pragma unroll
            for (int ks = 0; ks < 2; ++ks)
                a0[mf * 2 + ks] = *(const half8*)(Ac + ((wr * 2 + mf) * 2 + ks) * 1024 + lane * 16);
#pragma unroll
        for (int nf = 0; nf < 2; ++nf)
#pragma unroll
            for (int ks = 0; ks < 2; ++ks)
                b0[nf * 2 + ks] = *(const half8*)(Bc + (ks * 8 + wc * 2 + nf) * 1024 + lane * 16);
        if (kt < 31) {
            B_STAGE(kt + 1, Bn);   // 4 gload_lds, drained in phase 3
            A_LOAD(kt + 1);        // 2 global loads, consumed in phase 3
        }
        __builtin_amdgcn_s_barrier();
        asm volatile("s_waitcnt lgkmcnt(0)" ::: "memory");
        __builtin_amdgcn_sched_barrier(0);
        __builtin_amdgcn_s_setprio(1);
#pragma unroll
        for (int mf = 0; mf < 2; ++mf)
#pragma unroll
            for (int nf = 0; nf < 2; ++nf)
#pragma unroll
                for (int ks = 0; ks < 2; ++ks)
                    acc1[mf][nf] = __builtin_amdgcn_mfma_f32_32x32x16_f16(
                        a0[mf * 2 + ks], b0[nf * 2 + ks], acc1[mf][nf], 0, 0, 0);
        __builtin_amdgcn_s_setprio(0);
        __builtin_amdgcn_s_barrier();

        // ================= phase 2: acc2 += a0*b1 =================
#pragma unroll
        for (int nf = 0; nf < 2; ++nf)
#pragma unroll
            for (int ks = 0; ks < 2; ++ks)
                b1f[nf * 2 + ks] = *(const half8*)(Bc + ((2 + ks) * 8 + wc * 2 + nf) * 1024 + lane * 16);
        __builtin_amdgcn_s_barrier();
        asm volatile("s_waitcnt lgkmcnt(0)" ::: "memory");
        __builtin_amdgcn_sched_barrier(0);
        __builtin_amdgcn_s_setprio(1);
#pragma unroll
        for (int mf = 0; mf < 2; ++mf)
#pragma unroll
            for (int nf = 0; nf < 2; ++nf)
#pragma unroll
                for (int ks = 0; ks < 2; ++ks)
                    acc2[mf][nf] = __builtin_amdgcn_mfma_f32_32x32x16_f16(
                        a0[mf * 2 + ks], b1f[nf * 2 + ks], acc2[mf][nf], 0, 0, 0);
        __builtin_amdgcn_s_setprio(0);
        __builtin_amdgcn_s_barrier();

        // ================= phase 3: acc2 += a1*b0 =================
#pragma unroll
        for (int mf = 0; mf < 2; ++mf)
#pragma unroll
            for (int ks = 0; ks < 2; ++ks)
                a1[mf * 2 + ks] = *(const half8*)(Ac + ((4 + wr * 2 + mf) * 2 + ks) * 1024 + lane * 16);
        if (kt < 31) {
            A_CONVERT_WRITE(An);   // compiler waits the A globals; 2 ds_writes
            asm volatile("s_waitcnt vmcnt(0)" ::: "memory");  // B-DMA issued 2 phases ago
            __builtin_amdgcn_sched_barrier(0);
        }
        __builtin_amdgcn_s_barrier();
        asm volatile("s_waitcnt lgkmcnt(0)" ::: "memory");   // covers a1 reads + A writes
        __builtin_amdgcn_sched_barrier(0);
        __builtin_amdgcn_s_setprio(1);
#pragma unroll
        for (int mf = 0; mf < 2; ++mf)
#pragma unroll
            for (int nf = 0; nf < 2; ++nf)
#pragma unroll
                for (int ks = 0; ks < 2; ++ks)
                    acc2[mf][nf] = __builtin_amdgcn_mfma_f32_32x32x16_f16(
                        a1[mf * 2 + ks], b0[nf * 2 + ks], acc2[mf][nf], 0, 0, 0);
        __builtin_amdgcn_s_setprio(0);
        __builtin_amdgcn_s_barrier();   // flip barrier

        cur ^= 1;
    }

    // ---- epilogue: h = acc1 + acc2/2048 + b1; exact gelu; *W2; reduce 256 cols ----
    __syncthreads();
    float* red = (float*)smem;          // [128][132]
    float b1v[2], w2v[2];
#pragma unroll
    for (int nfl = 0; nfl < 2; ++nfl) {
        int c = nb * 256 + wc * 64 + nfl * 32 + (lane & 31);
        b1v[nfl] = b1[c];
        w2v[nfl] = W2[c];
    }
#pragma unroll
    for (int mf = 0; mf < 2; ++mf) {
#pragma unroll
        for (int i = 0; i < 16; ++i) {
            float s = 0.f;
#pragma unroll
            for (int nfl = 0; nfl < 2; ++nfl) {
                float h = acc1[mf][nfl][i] + acc2[mf][nfl][i] * (1.0f / 2048.0f) + b1v[nfl];
                float g = 0.5f * h * (1.0f + erff(h * 0.70710678118654752f));
                s = fmaf(g, w2v[nfl], s);
            }
            int row = wr * 64 + mf * 32 + (i & 3) + 8 * (i >> 2) + 4 * (lane >> 5);
            red[row * 132 + wc * 32 + (lane & 31)] = s;
        }
    }
    __syncthreads();
    if (t < 128) {
        float s = 0.f;
#pragma unroll
        for (int c = 0; c < 128; ++c) s += red[t * 132 + c];
        sparts[(size_t)nb * tot_tokens + m0 + t] = s;
    }
}

// ---- per-segment top-quota selection + gather (scores = sum of 2 partials) ----
__global__ void select_gather_kernel(const float* __restrict__ X,
                                     const float* __restrict__ sparts,
                                     float* __restrict__ out,
                                     int N, int seg_len, int quota, int n_seg,
                                     int tot_tokens) {
    const int seg = blockIdx.x;
    const int b   = blockIdx.y;
    __shared__ float sc[64];
    __shared__ int sel_idx[64];
    const int t = threadIdx.x;
    if (t < seg_len) {
        size_t tok = (size_t)b * N + (size_t)seg * seg_len + t;
        sc[t] = sparts[tok] + sparts[tok + tot_tokens];
    }
    __syncthreads();
    if (t == 0) {
        unsigned long long mask = 0ull;
        for (int it = 0; it < quota; ++it) {
            float best = 0.f;
            int bi = 0;
            bool found = false;
            for (int i = 0; i < seg_len; ++i) {
                if (!((mask >> i) & 1ull)) {
                    if (!found || sc[i] > best) { best = sc[i]; bi = i; found = true; }
                }
            }
            mask |= (1ull << bi);
        }
        int c = 0;
        for (int i = 0; i < seg_len; ++i)
            if ((mask >> i) & 1ull) sel_idx[c++] = i;  // ascending == sorted output
    }
    __syncthreads();
    const size_t HV = H_DIM / 4;
    const float4* xb = (const float4*)X + ((size_t)b * N + (size_t)seg * seg_len) * HV;
    float4* ob = (float4*)out + ((size_t)b * n_seg * quota + (size_t)seg * quota) * HV;
    for (int j = 0; j < quota; ++j) {
        const float4* srow = xb + (size_t)sel_idx[j] * HV;
        float4* drow = ob + (size_t)j * HV;
        for (int c = t; c < (int)HV; c += blockDim.x) drow[c] = srow[c];
    }
}

extern "C" void kernel_launch(void* const* d_in, const int* in_sizes, int n_in,
                              void* d_out, int out_size, void* d_ws, size_t ws_size,
                              hipStream_t stream) {
    const float* X  = (const float*)d_in[0];
    const float* W1 = (const float*)d_in[1];
    const float* b1 = (const float*)d_in[2];
    const float* W2 = (const float*)d_in[3];
    float* out = (float*)d_out;

    const int Hh = in_sizes[2];                        // 512
    const int H  = Hh * 2;                             // 1024
    const long long TOT = (long long)in_sizes[0] / H;  // 147456 tokens
    const int B = 256;
    const int N = (int)(TOT / B);                      // 576
    const int n_seg = 32;
    const int seg_len = N / n_seg;                     // 18
    const int rows_per_b = out_size / (B * H);         // 288
    const int quota = rows_per_b / n_seg;              // 9

    _Float16* Bpack = (_Float16*)d_ws;                                  // 2 MB
    float* sparts   = (float*)((char*)d_ws + (size_t)2 * 1024 * 1024);  // 2*TOT floats

    hipLaunchKernelGGL(pack_w1_kernel, dim3(256), dim3(256), 0, stream, W1, Bpack);

    const int nwg = (int)(TOT / 128) * 2;              // 2304, divisible by 8
    hipLaunchKernelGGL(score_mfma_kernel, dim3(nwg), dim3(512), 0, stream,
                       X, Bpack, b1, W2, sparts, (int)TOT);

    dim3 sg(n_seg, B);
    hipLaunchKernelGGL(select_gather_kernel, sg, dim3(256), 0, stream,
                       X, sparts, out, N, seg_len, quota, n_seg, (int)TOT);
}

// Round 7
// 587.799 us; speedup vs baseline: 1.4412x; 1.2550x over previous
//
#include <hip/hip_runtime.h>
#include <math.h>

#define H_DIM 1024
#define SEG_LEN 18
#define N_SEG 32
#define QUOTA 9
#define GAP_THR 8.0e-4f

typedef _Float16 half8 __attribute__((ext_vector_type(8)));
typedef _Float16 half4 __attribute__((ext_vector_type(4)));
typedef float f32x4 __attribute__((ext_vector_type(4)));
typedef float f32x16 __attribute__((ext_vector_type(16)));

__device__ __forceinline__ void gload_lds16(const void* g, void* l) {
    __builtin_amdgcn_global_load_lds((const __attribute__((address_space(1))) uint32_t*)g,
                                     (__attribute__((address_space(3))) uint32_t*)l,
                                     16, 0, 0);
}

__device__ __forceinline__ float gelu_exact(float h) {
    return 0.5f * h * (1.0f + erff(h * 0.70710678118654752f));
}

// ---- pack W1 [512][1024] fp32 into two layouts ----
// B32 (2 MB): 32x32x16-frag order, 2 exact-split fp16 planes:
//   half-off = kt*32768 + nb*16384 + ksub*4096 + nf*512 + (hi*32+nlo)*8 + j  (+8192 plane1)
// B16 (1 MB): 16x16x32-frag order, plane-0 only:
//   half-off = (ks*32 + nf16)*512 + lane*8 + j
__global__ void pack_w1_kernel(const float* __restrict__ W1,
                               _Float16* __restrict__ B32,
                               _Float16* __restrict__ B16) {
    const int bid = blockIdx.x, t = threadIdx.x;
    if (bid < 256) {
        int tid = bid * 256 + t;                 // 512 n x 128 k-octets
        int q = tid & 127, n = tid >> 7;
        int kt = q >> 2, ksub = (q >> 1) & 1, hi = q & 1;
        int nb = n >> 8, nf = (n >> 5) & 7, nlo = n & 31;
        const float* src = W1 + (size_t)n * H_DIM + q * 8;
        float4 v0 = *(const float4*)src, v1 = *(const float4*)(src + 4);
        float xs[8] = {v0.x, v0.y, v0.z, v0.w, v1.x, v1.y, v1.z, v1.w};
        half8 h0, h1;
#pragma unroll
        for (int j = 0; j < 8; ++j) {
            _Float16 a = (_Float16)xs[j];
            float r = xs[j] - (float)a;
            h0[j] = a;
            h1[j] = (_Float16)(r * 2048.0f);
        }
        size_t base = (size_t)kt * 32768 + nb * 16384 + ksub * 4096 + nf * 512
                    + (size_t)(hi * 32 + nlo) * 8;
        *(half8*)(B32 + base) = h0;
        *(half8*)(B32 + base + 8192) = h1;
    } else {
        int tid = (bid - 256) * 256 + t;
        int lane = tid & 63, nf = (tid >> 6) & 31, ks = tid >> 11;
        int n = nf * 16 + (lane & 15), k0 = ks * 32 + (lane >> 4) * 8;
        const float* src = W1 + (size_t)n * H_DIM + k0;
        float4 v0 = *(const float4*)src, v1 = *(const float4*)(src + 4);
        float xs[8] = {v0.x, v0.y, v0.z, v0.w, v1.x, v1.y, v1.z, v1.w};
        half8 h0;
#pragma unroll
        for (int j = 0; j < 8; ++j) h0[j] = (_Float16)xs[j];
        *(half8*)(B16 + ((size_t)(ks * 32 + nf)) * 512 + lane * 8) = h0;
    }
}

// ---- stage-1 scorer: SINGLE-pass fp16 MFMA (screen estimate) ----
// R3-proven structure: 64 rows x 256 cols (nb half), 4 waves of 64x64, dbuf,
// counted vmcnt. LDS: As 2x4KB + Bs 2x16KB = 40 KB; red overlays. 3 blocks/CU.
__global__ __launch_bounds__(256, 3)
void stage1_kernel(const float* __restrict__ X, const _Float16* __restrict__ B16,
                   const float* __restrict__ b1, const float* __restrict__ W2,
                   float* __restrict__ sparts, int tot) {
    __shared__ __align__(16) char smem[40960];
    const int t = threadIdx.x, w = t >> 6, lane = t & 63;
    const int nb = blockIdx.y;
    const size_t m0 = (size_t)blockIdx.x * 64;
    const int arow = w * 16 + (t & 15);
    const int aq = (t >> 4) & 3;
    const int aslot = t & 63;
    const float* aptr = X + (m0 + arow) * H_DIM + aq * 8;

    f32x4 acc[4][4] = {};
    float4 av0, av1;

#define S1_CONVERT(buf)                                                         \
    do {                                                                        \
        float xs[8] = {av0.x, av0.y, av0.z, av0.w, av1.x, av1.y, av1.z, av1.w}; \
        half8 h0;                                                               \
        _Pragma("unroll") for (int j = 0; j < 8; ++j) h0[j] = (_Float16)xs[j];  \
        *(half8*)(smem + ((buf) * 4 + w) * 1024 + aslot * 16) = h0;             \
    } while (0)

#define S1_STAGE(ks, buf)                                                       \
    do {                                                                        \
        _Pragma("unroll") for (int r = 0; r < 4; ++r) {                         \
            int idx = r * 256 + t;                                              \
            gload_lds16(B16 + ((size_t)((ks) * 32 + nb * 16 + (idx >> 6))) * 512 \
                            + (idx & 63) * 8,                                   \
                        smem + 8192 + (buf) * 16384 + idx * 16);                \
        }                                                                       \
    } while (0)

    av0 = *(const float4*)aptr;
    av1 = *(const float4*)(aptr + 4);
    S1_CONVERT(0);                 // waits av only (oldest)
    S1_STAGE(0, 0);
    __builtin_amdgcn_sched_barrier(0);
    av0 = *(const float4*)(aptr + 32);
    av1 = *(const float4*)(aptr + 36);
    __builtin_amdgcn_sched_barrier(0);
    asm volatile("s_waitcnt vmcnt(2) lgkmcnt(0)" ::: "memory");
    __builtin_amdgcn_sched_barrier(0);
    __builtin_amdgcn_s_barrier();

    int cur = 0;
    for (int ks = 0; ks < 32; ++ks) {
        const int nxt = cur ^ 1;
        if (ks < 31) {
            S1_STAGE(ks + 1, nxt);           // 4 gload_lds (newest vmem)
            __builtin_amdgcn_sched_barrier(0);
            S1_CONVERT(nxt);                 // waits av(ks+1) (older) -> gloads fly
            if (ks < 30) {
                av0 = *(const float4*)(aptr + (ks + 2) * 32);
                av1 = *(const float4*)(aptr + (ks + 2) * 32 + 4);
            }
            __builtin_amdgcn_sched_barrier(0);
        }
        half8 aA[4], bA[4];
#pragma unroll
        for (int mf = 0; mf < 4; ++mf)
            aA[mf] = *(const half8*)(smem + (cur * 4 + mf) * 1024 + lane * 16);
#pragma unroll
        for (int nf = 0; nf < 4; ++nf)
            bA[nf] = *(const half8*)(smem + 8192 + cur * 16384 + (w * 4 + nf) * 1024 + lane * 16);

        __builtin_amdgcn_s_setprio(1);
#pragma unroll
        for (int mf = 0; mf < 4; ++mf)
#pragma unroll
            for (int nf = 0; nf < 4; ++nf)
                acc[mf][nf] = __builtin_amdgcn_mfma_f32_16x16x32_f16(aA[mf], bA[nf], acc[mf][nf], 0, 0, 0);
        __builtin_amdgcn_s_setprio(0);

        if (ks < 31) {
            if (ks < 30) {
                asm volatile("s_waitcnt vmcnt(2) lgkmcnt(0)" ::: "memory");
            } else {
                asm volatile("s_waitcnt vmcnt(0) lgkmcnt(0)" ::: "memory");
            }
            __builtin_amdgcn_sched_barrier(0);
            __builtin_amdgcn_s_barrier();
        }
        cur = nxt;
    }

    // epilogue: h = acc + b1; gelu; *W2; reduce 256 cols -> partial scores
    __syncthreads();
    float* red = (float*)smem;  // [4][64][17]
    const int hi = lane >> 4, lc = lane & 15;
    float b1v[4], w2v[4];
#pragma unroll
    for (int nf = 0; nf < 4; ++nf) {
        int c = nb * 256 + w * 64 + nf * 16 + lc;
        b1v[nf] = b1[c];
        w2v[nf] = W2[c];
    }
#pragma unroll
    for (int mf = 0; mf < 4; ++mf) {
#pragma unroll
        for (int i = 0; i < 4; ++i) {
            float s = 0.f;
#pragma unroll
            for (int nf = 0; nf < 4; ++nf) {
                float h = acc[mf][nf][i] + b1v[nf];
                s = fmaf(gelu_exact(h), w2v[nf], s);
            }
            red[(w * 64 + mf * 16 + hi * 4 + i) * 17 + lc] = s;
        }
    }
    __syncthreads();
    if (t < 64) {
        float s = 0.f;
#pragma unroll
        for (int ww = 0; ww < 4; ++ww)
#pragma unroll
            for (int c = 0; c < 16; ++c) s += red[(ww * 64 + t) * 17 + c];
        sparts[(size_t)nb * tot + m0 + t] = s;
    }
}

// ---- flag + provisional select from screen scores ----
__global__ void flag_select_kernel(const float* __restrict__ sparts, int tot,
                                   int* __restrict__ sel_buf,
                                   int* __restrict__ flag_list,
                                   int* __restrict__ counter, int N, int nseg_tot) {
    int seg = blockIdx.x * 256 + threadIdx.x;
    if (seg >= nseg_tot) return;
    int b = seg >> 5, s = seg & 31;
    size_t base = (size_t)b * N + s * SEG_LEN;
    float sc[SEG_LEN];
#pragma unroll
    for (int j = 0; j < SEG_LEN; ++j) sc[j] = sparts[base + j] + sparts[base + j + tot];
    unsigned mask = 0;
    float best9 = 0.f;
    for (int it = 0; it < QUOTA; ++it) {
        float best = 0.f; int bi = 0; bool found = false;
        for (int i = 0; i < SEG_LEN; ++i) if (!((mask >> i) & 1u)) {
            if (!found || sc[i] > best) { best = sc[i]; bi = i; found = true; }
        }
        mask |= 1u << bi;
        best9 = best;
    }
    float best10 = 0.f; bool f10 = false;
    for (int i = 0; i < SEG_LEN; ++i) if (!((mask >> i) & 1u)) {
        if (!f10 || sc[i] > best10) { best10 = sc[i]; f10 = true; }
    }
    if (best9 - best10 > GAP_THR) {
        int c = 0;
        for (int i = 0; i < SEG_LEN; ++i)
            if ((mask >> i) & 1u) sel_buf[(size_t)seg * QUOTA + (c++)] = i;
    } else {
        int p = atomicAdd(counter, 1);
        flag_list[p] = seg;
    }
}

// ---- exact recheck (fp16-split 3-pass, proven numerics) of flagged segments ----
// block = 3 flagged segments (54 rows padded to 64) x 512 cols, 8 waves 64x64.
// LDS: A 8 KB + B 64 KB = 72 KB; epilogue red[8][64][33]+sx overlays.
__global__ __launch_bounds__(512, 2)
void recheck_kernel(const float* __restrict__ X, const _Float16* __restrict__ B32,
                    const float* __restrict__ b1, const float* __restrict__ W2,
                    const int* __restrict__ flag_list, const int* __restrict__ counter,
                    int* __restrict__ sel_buf, int N) {
    const int count = *counter;
    const int jb = blockIdx.x;
    if (jb * 3 >= count) return;
    __shared__ __align__(16) char smem[73728];
    const int t = threadIdx.x, w = t >> 6, lane = t & 63;

    // A staging: row r_ = t>>3 (0..63), 4-float k-quad kq8 = t&7 (uniform all waves)
    const int r_ = t >> 3, kq8 = t & 7;
    int q = r_ / 18, rr = r_ % 18;
    if (r_ >= 54) { q = 2; rr = 0; }          // padding rows: harmless duplicates
    int li = jb * 3 + q; if (li >= count) li = count - 1;
    const int sg = flag_list[li];
    const float* aRow = X + ((size_t)(sg >> 5) * N + (sg & 31) * SEG_LEN + rr) * H_DIM + kq8 * 4;
    const int rg = r_ >> 5, aks = kq8 >> 2, ahi = (kq8 >> 1) & 1;
    const int aoff = (rg * 2 + aks) * 1024 + (ahi * 32 + (r_ & 31)) * 16 + (kq8 & 1) * 8;

    f32x16 acc1[2][2] = {};
    f32x16 acc2[2][2] = {};
    float4 av = *(const float4*)aRow;

    for (int kt = 0; kt < 32; ++kt) {
        // stage B(kt): 64 KB linear from B32
#pragma unroll
        for (int r8 = 0; r8 < 8; ++r8) {
            int idx = r8 * 512 + t;
            gload_lds16(B32 + (size_t)kt * 32768 + (size_t)idx * 8,
                        smem + 8192 + (size_t)idx * 16);
        }
        {   // convert+write A(kt): waits av (older than the 8 gloads)
            float xs[4] = {av.x, av.y, av.z, av.w};
            half4 h0, h1;
#pragma unroll
            for (int j = 0; j < 4; ++j) {
                _Float16 a = (_Float16)xs[j];
                float r = xs[j] - (float)a;
                h0[j] = a;
                h1[j] = (_Float16)(r * 2048.0f);
            }
            *(half4*)(smem + aoff) = h0;
            *(half4*)(smem + 4096 + aoff) = h1;
        }
        int ktn = kt < 31 ? kt + 1 : 31;       // clamped re-read keeps vmcnt uniform
        av = *(const float4*)(aRow + ktn * 32);
        asm volatile("s_waitcnt vmcnt(1) lgkmcnt(0)" ::: "memory");
        __builtin_amdgcn_sched_barrier(0);
        __builtin_amdgcn_s_barrier();

        half8 a0[4], a1[4], b0[4], b1f[4];
#pragma unroll
        for (int mf = 0; mf < 2; ++mf)
#pragma unroll
            for (int ks2 = 0; ks2 < 2; ++ks2) {
                a0[mf * 2 + ks2] = *(const half8*)(smem + (mf * 2 + ks2) * 1024 + lane * 16);
                a1[mf * 2 + ks2] = *(const half8*)(smem + 4096 + (mf * 2 + ks2) * 1024 + lane * 16);
            }
        const char* bb = smem + 8192 + (w >> 2) * 32768;
#pragma unroll
        for (int nfl = 0; nfl < 2; ++nfl)
#pragma unroll
            for (int ks2 = 0; ks2 < 2; ++ks2) {
                b0[nfl * 2 + ks2]  = *(const half8*)(bb + ks2 * 8192 + ((w & 3) * 2 + nfl) * 1024 + lane * 16);
                b1f[nfl * 2 + ks2] = *(const half8*)(bb + 16384 + ks2 * 8192 + ((w & 3) * 2 + nfl) * 1024 + lane * 16);
            }
        __builtin_amdgcn_s_setprio(1);
#pragma unroll
        for (int mf = 0; mf < 2; ++mf)
#pragma unroll
            for (int nfl = 0; nfl < 2; ++nfl)
#pragma unroll
                for (int ks2 = 0; ks2 < 2; ++ks2)
                    acc1[mf][nfl] = __builtin_amdgcn_mfma_f32_32x32x16_f16(
                        a0[mf * 2 + ks2], b0[nfl * 2 + ks2], acc1[mf][nfl], 0, 0, 0);
#pragma unroll
        for (int mf = 0; mf < 2; ++mf)
#pragma unroll
            for (int nfl = 0; nfl < 2; ++nfl)
#pragma unroll
                for (int ks2 = 0; ks2 < 2; ++ks2)
                    acc2[mf][nfl] = __builtin_amdgcn_mfma_f32_32x32x16_f16(
                        a0[mf * 2 + ks2], b1f[nfl * 2 + ks2], acc2[mf][nfl], 0, 0, 0);
#pragma unroll
        for (int mf = 0; mf < 2; ++mf)
#pragma unroll
            for (int nfl = 0; nfl < 2; ++nfl)
#pragma unroll
                for (int ks2 = 0; ks2 < 2; ++ks2)
                    acc2[mf][nfl] = __builtin_amdgcn_mfma_f32_32x32x16_f16(
                        a1[mf * 2 + ks2], b0[nfl * 2 + ks2], acc2[mf][nfl], 0, 0, 0);
        __builtin_amdgcn_s_setprio(0);
        __builtin_amdgcn_s_barrier();          // all reads done before next staging
    }

    // epilogue: exact scores, then in-block top-9 per flagged segment
    __syncthreads();
    float* red = (float*)smem;                 // [8][64][33]
    float b1v[2], w2v[2];
#pragma unroll
    for (int nfl = 0; nfl < 2; ++nfl) {
        int c = (w >> 2) * 256 + ((w & 3) * 2 + nfl) * 32 + (lane & 31);
        b1v[nfl] = b1[c];
        w2v[nfl] = W2[c];
    }
#pragma unroll
    for (int mf = 0; mf < 2; ++mf)
#pragma unroll
        for (int i = 0; i < 16; ++i) {
            float s = 0.f;
#pragma unroll
            for (int nfl = 0; nfl < 2; ++nfl) {
                float h = acc1[mf][nfl][i] + acc2[mf][nfl][i] * (1.0f / 2048.0f) + b1v[nfl];
                s = fmaf(gelu_exact(h), w2v[nfl], s);
            }
            int row = mf * 32 + (i & 3) + 8 * (i >> 2) + 4 * (lane >> 5);
            red[(w * 64 + row) * 33 + (lane & 31)] = s;
        }
    __syncthreads();
    float* sx = (float*)(smem + 67584);        // [64]
    if (t < 64) {
        float s = 0.f;
        for (int ww = 0; ww < 8; ++ww)
#pragma unroll
            for (int lc = 0; lc < 32; ++lc) s += red[(ww * 64 + t) * 33 + lc];
        sx[t] = s;
    }
    __syncthreads();
    if (t < 3 && jb * 3 + t < count) {
        int sg2 = flag_list[jb * 3 + t];
        const float* sv = sx + t * SEG_LEN;
        unsigned mask = 0;
        for (int it = 0; it < QUOTA; ++it) {
            float best = 0.f; int bi = 0; bool found = false;
            for (int i = 0; i < SEG_LEN; ++i) if (!((mask >> i) & 1u)) {
                if (!found || sv[i] > best) { best = sv[i]; bi = i; found = true; }
            }
            mask |= 1u << bi;
        }
        int c = 0;
        for (int i = 0; i < SEG_LEN; ++i)
            if ((mask >> i) & 1u) sel_buf[(size_t)sg2 * QUOTA + (c++)] = i;
    }
}

// ---- final gather of selected rows ----
__global__ void gather_kernel(const float* __restrict__ X, const int* __restrict__ sel_buf,
                              float* __restrict__ out, int N) {
    const int seg = blockIdx.x, b = blockIdx.y, t = threadIdx.x;
    const int* sel = sel_buf + ((size_t)b * N_SEG + seg) * QUOTA;
    const float4* xb = (const float4*)X + ((size_t)b * N + seg * SEG_LEN) * (H_DIM / 4);
    float4* ob = (float4*)out + ((size_t)b * N_SEG * QUOTA + seg * QUOTA) * (H_DIM / 4);
#pragma unroll
    for (int j = 0; j < QUOTA; ++j) {
        int r = sel[j];
        ob[(size_t)j * (H_DIM / 4) + t] = xb[(size_t)r * (H_DIM / 4) + t];
    }
}

extern "C" void kernel_launch(void* const* d_in, const int* in_sizes, int n_in,
                              void* d_out, int out_size, void* d_ws, size_t ws_size,
                              hipStream_t stream) {
    const float* X  = (const float*)d_in[0];
    const float* W1 = (const float*)d_in[1];
    const float* b1 = (const float*)d_in[2];
    const float* W2 = (const float*)d_in[3];
    // d_in[4] (b2): constant shift, selection-invariant; d_in[5]: quota via out_size
    float* out = (float*)d_out;

    const int Hh = in_sizes[2];                        // 512
    const int H  = Hh * 2;                             // 1024
    const long long TOT = (long long)in_sizes[0] / H;  // 147456 tokens
    const int B = 256;
    const int N = (int)(TOT / B);                      // 576
    const int nseg_tot = B * N_SEG;                    // 8192

    char* ws = (char*)d_ws;
    _Float16* B32 = (_Float16*)(ws + 0);               // 2 MB
    _Float16* B16 = (_Float16*)(ws + 2097152);         // 1 MB
    float* sparts = (float*)(ws + 3145728);            // 2*TOT f32
    int* sel_buf  = (int*)(ws + 4325376);              // 8192*9
    int* flag_list= (int*)(ws + 4620288);              // 8192
    int* counter  = (int*)(ws + 4653056);

    hipMemsetAsync(counter, 0, 16, stream);

    hipLaunchKernelGGL(pack_w1_kernel, dim3(512), dim3(256), 0, stream, W1, B32, B16);

    hipLaunchKernelGGL(stage1_kernel, dim3((unsigned)(TOT / 64), 2), dim3(256), 0, stream,
                       X, B16, b1, W2, sparts, (int)TOT);

    hipLaunchKernelGGL(flag_select_kernel, dim3((nseg_tot + 255) / 256), dim3(256), 0, stream,
                       sparts, (int)TOT, sel_buf, flag_list, counter, N, nseg_tot);

    hipLaunchKernelGGL(recheck_kernel, dim3((nseg_tot + 2) / 3), dim3(512), 0, stream,
                       X, B32, b1, W2, flag_list, counter, sel_buf, N);

    hipLaunchKernelGGL(gather_kernel, dim3(N_SEG, B), dim3(256), 0, stream,
                       X, sel_buf, out, N);
}